// Round 2
// baseline (496.538 us; speedup 1.0000x reference)
//
#include <hip/hip_runtime.h>

// Problem dims
#define B_   16
#define M_   2048
#define D_   128
#define H_   256
#define K_   64
#define ROWS (B_ * M_)   // 32768

typedef short short8 __attribute__((ext_vector_type(8)));
typedef float f32x4  __attribute__((ext_vector_type(4)));

// ws layout (in short/bf16 elements)
static constexpr size_t OFF_QHI = 0;                           // [ROWS][64]
static constexpr size_t OFF_QLO = (size_t)ROWS * K_;
static constexpr size_t OFF_KHI = 2 * (size_t)ROWS * K_;
static constexpr size_t OFF_KLO = 3 * (size_t)ROWS * K_;
static constexpr size_t OFF_W1H = 4 * (size_t)ROWS * K_;       // [2][H_][D_]
static constexpr size_t OFF_W1L = OFF_W1H + 2 * (size_t)D_ * H_;
static constexpr size_t OFF_W2H = OFF_W1L + 2 * (size_t)D_ * H_;  // [2][K_][H_]
static constexpr size_t OFF_W2L = OFF_W2H + 2 * (size_t)H_ * K_;
// total ≈ 8.59M shorts ≈ 17.2 MB

static __device__ __forceinline__ float bf2f(short u) {
    union { unsigned int u; float f; } c;
    c.u = ((unsigned int)(unsigned short)u) << 16;
    return c.f;
}
static __device__ __forceinline__ short f2bf(float f) {
    union { float f; unsigned int u; } c; c.f = f;
    unsigned int u = c.u + 0x7fffu + ((c.u >> 16) & 1u);   // RNE
    return (short)(u >> 16);
}
static __device__ __forceinline__ void split2(float v, short& hi, short& lo) {
    hi = f2bf(v);
    lo = f2bf(v - bf2f(hi));
}
static __device__ __forceinline__ f32x4 mfma16(short8 a, short8 b, f32x4 c) {
    return __builtin_amdgcn_mfma_f32_16x16x32_bf16(a, b, c, 0, 0, 0);
}

// ---------------------------------------------------------------------------
// k0: transpose + hi/lo split weights (fp32 -> bf16 planes)
//   W1 [D][H] -> W1T [H][D] ; W2 [H][K] -> W2T [K][H]
// ---------------------------------------------------------------------------
__global__ __launch_bounds__(256) void prep_w(
    const float* __restrict__ qW1, const float* __restrict__ kW1,
    const float* __restrict__ qW2, const float* __restrict__ kW2,
    short* __restrict__ ws)
{
    const int which = blockIdx.y;
    const float* src; short* dhi; short* dlo; int N, Kd;
    if (which == 0)      { src = qW1; dhi = ws + OFF_W1H;            dlo = ws + OFF_W1L;            N = H_; Kd = D_; }
    else if (which == 1) { src = kW1; dhi = ws + OFF_W1H + D_ * H_;  dlo = ws + OFF_W1L + D_ * H_;  N = H_; Kd = D_; }
    else if (which == 2) { src = qW2; dhi = ws + OFF_W2H;            dlo = ws + OFF_W2L;            N = K_; Kd = H_; }
    else                 { src = kW2; dhi = ws + OFF_W2H + H_ * K_;  dlo = ws + OFF_W2L + H_ * K_;  N = K_; Kd = H_; }
    int idx = blockIdx.x * 256 + threadIdx.x;
    if (idx < N * Kd) {
        int n = idx / Kd, k = idx % Kd;
        float v = src[(size_t)k * N + n];   // dst[n][k] = src[k][n]
        short hi, lo; split2(v, hi, lo);
        dhi[idx] = hi; dlo[idx] = lo;
    }
}

// ---------------------------------------------------------------------------
// k1: fused MLP per wave (16 rows), fp32 in, split-bf16 MFMA arithmetic.
//   h = relu(x@W1+b1); out = h@W2+b2 -> Q/K hi+lo bf16 planes in ws.
// Block = 128 thr (2 waves). grid = (ROWS/32, 2 heads).
// ---------------------------------------------------------------------------
__global__ __launch_bounds__(128) void mlp_kernel(
    const float* __restrict__ x,     // [ROWS][128] fp32
    short* __restrict__ ws,
    const float* __restrict__ qb1, const float* __restrict__ kb1,
    const float* __restrict__ qb2, const float* __restrict__ kb2)
{
    const int head = blockIdx.y;
    const short* W1H = ws + OFF_W1H + (size_t)head * (D_ * H_);  // [256][128]
    const short* W1L = ws + OFF_W1L + (size_t)head * (D_ * H_);
    const short* W2H = ws + OFF_W2H + (size_t)head * (H_ * K_);  // [64][256]
    const short* W2L = ws + OFF_W2L + (size_t)head * (H_ * K_);
    const float* b1  = head ? kb1 : qb1;
    const float* b2  = head ? kb2 : qb2;
    short* ohi       = ws + (head ? OFF_KHI : OFF_QHI);          // [ROWS][64]
    short* olo       = ws + (head ? OFF_KLO : OFF_QLO);

    const int tid  = threadIdx.x;
    const int w    = tid >> 6;        // wave 0..1
    const int lane = tid & 63;
    const int l15  = lane & 15;
    const int quad = lane >> 4;
    const int r0   = (blockIdx.x * 2 + w) * 16;   // this wave's 16 rows

    // per-wave h tile, split hi/lo; row stride 264 shorts (16B-aligned)
    __shared__ __align__(16) short hs[2][2][16][264];

    // ---- A-frags from x: A[m=l15][k=quad*8+j], split hi/lo ----
    short8 ah[4], al[4];
    const float* xrow = x + (size_t)(r0 + l15) * D_ + quad * 8;
    #pragma unroll
    for (int ks = 0; ks < 4; ++ks) {
        #pragma unroll
        for (int j = 0; j < 8; ++j) {
            short hi, lo; split2(xrow[ks * 32 + j], hi, lo);
            ah[ks][j] = hi; al[ks][j] = lo;
        }
    }

    // ---- GEMM1 ----
    #pragma unroll
    for (int jt = 0; jt < 16; ++jt) {             // 16 col-tiles of H=256
        f32x4 acc = {0.f, 0.f, 0.f, 0.f};
        const size_t wro = (size_t)(jt * 16 + l15) * D_ + quad * 8;
        #pragma unroll
        for (int ks = 0; ks < 4; ++ks) {
            short8 bh = *(const short8*)(W1H + wro + ks * 32);
            short8 bl = *(const short8*)(W1L + wro + ks * 32);
            acc = mfma16(ah[ks], bh, acc);
            acc = mfma16(al[ks], bh, acc);
            acc = mfma16(ah[ks], bl, acc);
        }
        float bias = b1[jt * 16 + l15];           // C col = l15
        #pragma unroll
        for (int r = 0; r < 4; ++r) {             // C row = quad*4+r
            float v = acc[r] + bias;
            v = v > 0.f ? v : 0.f;
            short hi, lo; split2(v, hi, lo);
            hs[w][0][quad * 4 + r][jt * 16 + l15] = hi;
            hs[w][1][quad * 4 + r][jt * 16 + l15] = lo;
        }
    }
    // no barrier: each wave reads only its own LDS region

    // ---- GEMM2: A-frags from hs ----
    short8 gh[8], gl[8];
    #pragma unroll
    for (int ks = 0; ks < 8; ++ks) {
        gh[ks] = *(const short8*)&hs[w][0][l15][ks * 32 + quad * 8];
        gl[ks] = *(const short8*)&hs[w][1][l15][ks * 32 + quad * 8];
    }
    #pragma unroll
    for (int jt = 0; jt < 4; ++jt) {              // 4 col-tiles of K=64
        f32x4 acc = {0.f, 0.f, 0.f, 0.f};
        const size_t wro = (size_t)(jt * 16 + l15) * H_ + quad * 8;
        #pragma unroll
        for (int ks = 0; ks < 8; ++ks) {
            short8 bh = *(const short8*)(W2H + wro + ks * 32);
            short8 bl = *(const short8*)(W2L + wro + ks * 32);
            acc = mfma16(gh[ks], bh, acc);
            acc = mfma16(gl[ks], bh, acc);
            acc = mfma16(gh[ks], bl, acc);
        }
        float bias = b2[jt * 16 + l15];
        #pragma unroll
        for (int r = 0; r < 4; ++r) {
            float v = acc[r] + bias;
            short hi, lo; split2(v, hi, lo);
            size_t oi = (size_t)(r0 + quad * 4 + r) * K_ + jt * 16 + l15;
            ohi[oi] = hi; olo[oi] = lo;
        }
    }
}

// ---------------------------------------------------------------------------
// k2: scores + max-division softmax. Block = 512 thr (8 waves), 16 Q-rows.
// Each wave: 16 j-tiles (256 cols), scores in VGPRs; single QK^T pass.
// grid = (M/16, B). fp32 output.
// ---------------------------------------------------------------------------
__global__ __launch_bounds__(512) void scores_kernel(
    const short* __restrict__ ws,
    float* __restrict__ out)          // [B][M][M] fp32
{
    const int bb  = blockIdx.y;
    const int i0  = blockIdx.x * 16;
    const int tid  = threadIdx.x;
    const int w    = tid >> 6;        // wave 0..7
    const int lane = tid & 63;
    const int l15  = lane & 15;
    const int quad = lane >> 4;

    const short* Qh = ws + OFF_QHI + (size_t)bb * M_ * K_;
    const short* Ql = ws + OFF_QLO + (size_t)bb * M_ * K_;
    const short* Kh = ws + OFF_KHI + (size_t)bb * M_ * K_;
    const short* Kl = ws + OFF_KLO + (size_t)bb * M_ * K_;

    // Q A-frags for rows i0..i0+15
    const size_t qo = (size_t)(i0 + l15) * K_ + quad * 8;
    short8 qh0 = *(const short8*)(Qh + qo);
    short8 qh1 = *(const short8*)(Qh + qo + 32);
    short8 ql0 = *(const short8*)(Ql + qo);
    short8 ql1 = *(const short8*)(Ql + qo + 32);

    f32x4 s[16];
    #pragma unroll
    for (int t = 0; t < 16; ++t) {
        const int j0 = (w * 16 + t) * 16;
        const size_t ko = (size_t)(j0 + l15) * K_ + quad * 8;
        short8 kh0 = *(const short8*)(Kh + ko);
        short8 kh1 = *(const short8*)(Kh + ko + 32);
        short8 kl0 = *(const short8*)(Kl + ko);
        short8 kl1 = *(const short8*)(Kl + ko + 32);
        f32x4 acc = {0.f, 0.f, 0.f, 0.f};
        acc = mfma16(qh0, kh0, acc);
        acc = mfma16(ql0, kh0, acc);
        acc = mfma16(qh0, kl0, acc);
        acc = mfma16(qh1, kh1, acc);
        acc = mfma16(ql1, kh1, acc);
        acc = mfma16(qh1, kl1, acc);
        s[t] = acc;
    }

    // ---- row max & min ----
    float mx[4], mn[4];
    #pragma unroll
    for (int r = 0; r < 4; ++r) { mx[r] = s[0][r]; mn[r] = s[0][r]; }
    #pragma unroll
    for (int t = 1; t < 16; ++t)
        #pragma unroll
        for (int r = 0; r < 4; ++r) {
            mx[r] = fmaxf(mx[r], s[t][r]);
            mn[r] = fminf(mn[r], s[t][r]);
        }
    #pragma unroll
    for (int r = 0; r < 4; ++r) {
        float a = mx[r], b = mn[r];
        a = fmaxf(a, __shfl_xor(a, 1));  b = fminf(b, __shfl_xor(b, 1));
        a = fmaxf(a, __shfl_xor(a, 2));  b = fminf(b, __shfl_xor(b, 2));
        a = fmaxf(a, __shfl_xor(a, 4));  b = fminf(b, __shfl_xor(b, 4));
        a = fmaxf(a, __shfl_xor(a, 8));  b = fminf(b, __shfl_xor(b, 8));
        mx[r] = a; mn[r] = b;
    }

    __shared__ float redmax[8][16], redmin[8][16], redsum[8][16];
    if (l15 == 0) {
        #pragma unroll
        for (int r = 0; r < 4; ++r) {
            redmax[w][quad * 4 + r] = mx[r];
            redmin[w][quad * 4 + r] = mn[r];
        }
    }
    __syncthreads();

    float invmax[4], zmax[4];
    #pragma unroll
    for (int r = 0; r < 4; ++r) {
        float mm = redmax[0][quad * 4 + r], nn = redmin[0][quad * 4 + r];
        #pragma unroll
        for (int ww = 1; ww < 8; ++ww) {
            mm = fmaxf(mm, redmax[ww][quad * 4 + r]);
            nn = fminf(nn, redmin[ww][quad * 4 + r]);
        }
        invmax[r] = 1.0f / mm;
        // z = qkt/rmax; true max of z = max(1, rmin/rmax) (handles rmax<0)
        zmax[r] = fmaxf(1.0f, nn * invmax[r]);
    }

    // ---- exp(z - zmax) in place + row sum ----
    float lsum[4] = {0.f, 0.f, 0.f, 0.f};
    #pragma unroll
    for (int t = 0; t < 16; ++t)
        #pragma unroll
        for (int r = 0; r < 4; ++r) {
            float e = __expf(s[t][r] * invmax[r] - zmax[r]);
            s[t][r] = e;
            lsum[r] += e;
        }
    #pragma unroll
    for (int r = 0; r < 4; ++r) {
        float v = lsum[r];
        v += __shfl_xor(v, 1); v += __shfl_xor(v, 2);
        v += __shfl_xor(v, 4); v += __shfl_xor(v, 8);
        lsum[r] = v;
    }
    if (l15 == 0) {
        #pragma unroll
        for (int r = 0; r < 4; ++r) redsum[w][quad * 4 + r] = lsum[r];
    }
    __syncthreads();

    float invsum[4];
    #pragma unroll
    for (int r = 0; r < 4; ++r) {
        float ss = 0.f;
        #pragma unroll
        for (int ww = 0; ww < 8; ++ww) ss += redsum[ww][quad * 4 + r];
        invsum[r] = 1.0f / ss;
    }

    // ---- normalize + store fp32 ----
    float* ob = out + (size_t)bb * M_ * M_;
    #pragma unroll
    for (int t = 0; t < 16; ++t) {
        const int j0 = (w * 16 + t) * 16;
        #pragma unroll
        for (int r = 0; r < 4; ++r) {
            size_t idx = (size_t)(i0 + quad * 4 + r) * M_ + j0 + l15;
            ob[idx] = s[t][r] * invsum[r];
        }
    }
}

// ---------------------------------------------------------------------------
extern "C" void kernel_launch(void* const* d_in, const int* in_sizes, int n_in,
                              void* d_out, int out_size, void* d_ws, size_t ws_size,
                              hipStream_t stream)
{
    (void)in_sizes; (void)n_in; (void)out_size; (void)ws_size;
    const float* x   = (const float*)d_in[0];
    const float* qW1 = (const float*)d_in[1];
    const float* qb1 = (const float*)d_in[2];
    const float* qW2 = (const float*)d_in[3];
    const float* qb2 = (const float*)d_in[4];
    const float* kW1 = (const float*)d_in[5];
    const float* kb1 = (const float*)d_in[6];
    const float* kW2 = (const float*)d_in[7];
    const float* kb2 = (const float*)d_in[8];
    short* ws  = (short*)d_ws;
    float* out = (float*)d_out;

    prep_w<<<dim3(128, 4), 256, 0, stream>>>(qW1, kW1, qW2, kW2, ws);
    mlp_kernel<<<dim3(ROWS / 32, 2), 128, 0, stream>>>(x, ws, qb1, kb1, qb2, kb2);
    scores_kernel<<<dim3(M_ / 16, B_), 512, 0, stream>>>(ws, out);
}

// Round 3
// 474.597 us; speedup vs baseline: 1.0462x; 1.0462x over previous
//
#include <hip/hip_runtime.h>

// Problem dims
#define B_   16
#define M_   2048
#define D_   128
#define H_   256
#define K_   64
#define ROWS (B_ * M_)   // 32768

typedef short short8 __attribute__((ext_vector_type(8)));
typedef float f32x4  __attribute__((ext_vector_type(4)));

// ws layout (in short/bf16 elements)
// Q stored hi+lo (removes q-side rounding); K stored hi only (error budget:
// k-rounding alone -> absmax ~1-2e-3 vs 1.55e-2 threshold).
static constexpr size_t OFF_QHI = 0;                           // [ROWS][64]
static constexpr size_t OFF_QLO = (size_t)ROWS * K_;
static constexpr size_t OFF_KHI = 2 * (size_t)ROWS * K_;
static constexpr size_t OFF_W1H = 3 * (size_t)ROWS * K_;       // [2][H_][D_]
static constexpr size_t OFF_W1L = OFF_W1H + 2 * (size_t)D_ * H_;
static constexpr size_t OFF_W2H = OFF_W1L + 2 * (size_t)D_ * H_;  // [2][K_][H_]
static constexpr size_t OFF_W2L = OFF_W2H + 2 * (size_t)H_ * K_;

static __device__ __forceinline__ float bf2f(short u) {
    union { unsigned int u; float f; } c;
    c.u = ((unsigned int)(unsigned short)u) << 16;
    return c.f;
}
static __device__ __forceinline__ short f2bf(float f) {
    union { float f; unsigned int u; } c; c.f = f;
    unsigned int u = c.u + 0x7fffu + ((c.u >> 16) & 1u);   // RNE
    return (short)(u >> 16);
}
static __device__ __forceinline__ void split2(float v, short& hi, short& lo) {
    hi = f2bf(v);
    lo = f2bf(v - bf2f(hi));
}
static __device__ __forceinline__ f32x4 mfma16(short8 a, short8 b, f32x4 c) {
    return __builtin_amdgcn_mfma_f32_16x16x32_bf16(a, b, c, 0, 0, 0);
}

// ---------------------------------------------------------------------------
// k0: transpose + hi/lo split weights (fp32 -> bf16 planes)
// ---------------------------------------------------------------------------
__global__ __launch_bounds__(256) void prep_w(
    const float* __restrict__ qW1, const float* __restrict__ kW1,
    const float* __restrict__ qW2, const float* __restrict__ kW2,
    short* __restrict__ ws)
{
    const int which = blockIdx.y;
    const float* src; short* dhi; short* dlo; int N, Kd;
    if (which == 0)      { src = qW1; dhi = ws + OFF_W1H;            dlo = ws + OFF_W1L;            N = H_; Kd = D_; }
    else if (which == 1) { src = kW1; dhi = ws + OFF_W1H + D_ * H_;  dlo = ws + OFF_W1L + D_ * H_;  N = H_; Kd = D_; }
    else if (which == 2) { src = qW2; dhi = ws + OFF_W2H;            dlo = ws + OFF_W2L;            N = K_; Kd = H_; }
    else                 { src = kW2; dhi = ws + OFF_W2H + H_ * K_;  dlo = ws + OFF_W2L + H_ * K_;  N = K_; Kd = H_; }
    int idx = blockIdx.x * 256 + threadIdx.x;
    if (idx < N * Kd) {
        int n = idx / Kd, k = idx % Kd;
        float v = src[(size_t)k * N + n];   // dst[n][k] = src[k][n]
        short hi, lo; split2(v, hi, lo);
        dhi[idx] = hi; dlo[idx] = lo;
    }
}

// ---------------------------------------------------------------------------
// k1: fused MLP per wave (16 rows), fp32 in, split-bf16 MFMA arithmetic.
//   head 0 -> Q hi+lo planes; head 1 -> K hi plane only.
// Block = 128 thr (2 waves). grid = (ROWS/32, 2 heads).
// ---------------------------------------------------------------------------
__global__ __launch_bounds__(128) void mlp_kernel(
    const float* __restrict__ x,     // [ROWS][128] fp32
    short* __restrict__ ws,
    const float* __restrict__ qb1, const float* __restrict__ kb1,
    const float* __restrict__ qb2, const float* __restrict__ kb2)
{
    const int head = blockIdx.y;
    const short* W1H = ws + OFF_W1H + (size_t)head * (D_ * H_);  // [256][128]
    const short* W1L = ws + OFF_W1L + (size_t)head * (D_ * H_);
    const short* W2H = ws + OFF_W2H + (size_t)head * (H_ * K_);  // [64][256]
    const short* W2L = ws + OFF_W2L + (size_t)head * (H_ * K_);
    const float* b1  = head ? kb1 : qb1;
    const float* b2  = head ? kb2 : qb2;
    short* ohi       = ws + (head ? OFF_KHI : OFF_QHI);          // [ROWS][64]
    short* olo       = ws + OFF_QLO;                             // head 0 only

    const int tid  = threadIdx.x;
    const int w    = tid >> 6;        // wave 0..1
    const int lane = tid & 63;
    const int l15  = lane & 15;
    const int quad = lane >> 4;
    const int r0   = (blockIdx.x * 2 + w) * 16;   // this wave's 16 rows

    // per-wave h tile, split hi/lo; row stride 264 shorts (16B-aligned)
    __shared__ __align__(16) short hs[2][2][16][264];

    // ---- A-frags from x: A[m=l15][k=quad*8+j], split hi/lo; float4 loads ----
    short8 ah[4], al[4];
    const float* xrow = x + (size_t)(r0 + l15) * D_ + quad * 8;
    #pragma unroll
    for (int ks = 0; ks < 4; ++ks) {
        float4 v0 = *(const float4*)(xrow + ks * 32);
        float4 v1 = *(const float4*)(xrow + ks * 32 + 4);
        float vv[8] = {v0.x, v0.y, v0.z, v0.w, v1.x, v1.y, v1.z, v1.w};
        #pragma unroll
        for (int j = 0; j < 8; ++j) {
            short hi, lo; split2(vv[j], hi, lo);
            ah[ks][j] = hi; al[ks][j] = lo;
        }
    }

    // ---- GEMM1 ----
    #pragma unroll
    for (int jt = 0; jt < 16; ++jt) {             // 16 col-tiles of H=256
        f32x4 acc = {0.f, 0.f, 0.f, 0.f};
        const size_t wro = (size_t)(jt * 16 + l15) * D_ + quad * 8;
        #pragma unroll
        for (int ks = 0; ks < 4; ++ks) {
            short8 bh = *(const short8*)(W1H + wro + ks * 32);
            short8 bl = *(const short8*)(W1L + wro + ks * 32);
            acc = mfma16(ah[ks], bh, acc);
            acc = mfma16(al[ks], bh, acc);
            acc = mfma16(ah[ks], bl, acc);
        }
        float bias = b1[jt * 16 + l15];           // C col = l15
        #pragma unroll
        for (int r = 0; r < 4; ++r) {             // C row = quad*4+r
            float v = acc[r] + bias;
            v = v > 0.f ? v : 0.f;
            short hi, lo; split2(v, hi, lo);
            hs[w][0][quad * 4 + r][jt * 16 + l15] = hi;
            hs[w][1][quad * 4 + r][jt * 16 + l15] = lo;
        }
    }
    // no barrier: each wave reads only its own LDS region

    // ---- GEMM2: A-frags from hs ----
    short8 gh[8], gl[8];
    #pragma unroll
    for (int ks = 0; ks < 8; ++ks) {
        gh[ks] = *(const short8*)&hs[w][0][l15][ks * 32 + quad * 8];
        gl[ks] = *(const short8*)&hs[w][1][l15][ks * 32 + quad * 8];
    }
    #pragma unroll
    for (int jt = 0; jt < 4; ++jt) {              // 4 col-tiles of K=64
        f32x4 acc = {0.f, 0.f, 0.f, 0.f};
        const size_t wro = (size_t)(jt * 16 + l15) * H_ + quad * 8;
        #pragma unroll
        for (int ks = 0; ks < 8; ++ks) {
            short8 bh = *(const short8*)(W2H + wro + ks * 32);
            short8 bl = *(const short8*)(W2L + wro + ks * 32);
            acc = mfma16(gh[ks], bh, acc);
            acc = mfma16(gl[ks], bh, acc);
            acc = mfma16(gh[ks], bl, acc);
        }
        float bias = b2[jt * 16 + l15];
        #pragma unroll
        for (int r = 0; r < 4; ++r) {
            float v = acc[r] + bias;
            size_t oi = (size_t)(r0 + quad * 4 + r) * K_ + jt * 16 + l15;
            if (head == 0) {
                short hi, lo; split2(v, hi, lo);
                ohi[oi] = hi; olo[oi] = lo;
            } else {
                ohi[oi] = f2bf(v);
            }
        }
    }
}

// ---------------------------------------------------------------------------
// k2: scores + max-division softmax. Block = 512 thr (8 waves), 16 Q-rows.
// Each wave: 16 j-tiles (256 cols), scores in VGPRs; single QK^T pass.
// grid = (M/16, B). fp32 output. Q = hi+lo, K = hi only (4 MFMAs/tile).
// __launch_bounds__(512,2): guarantee 256-VGPR budget, no heuristic spill.
// ---------------------------------------------------------------------------
__global__ __launch_bounds__(512, 2) void scores_kernel(
    const short* __restrict__ ws,
    float* __restrict__ out)          // [B][M][M] fp32
{
    const int bb  = blockIdx.y;
    const int i0  = blockIdx.x * 16;
    const int tid  = threadIdx.x;
    const int w    = tid >> 6;        // wave 0..7
    const int lane = tid & 63;
    const int l15  = lane & 15;
    const int quad = lane >> 4;

    const short* Qh = ws + OFF_QHI + (size_t)bb * M_ * K_;
    const short* Ql = ws + OFF_QLO + (size_t)bb * M_ * K_;
    const short* Kh = ws + OFF_KHI + (size_t)bb * M_ * K_;

    // Q A-frags for rows i0..i0+15
    const size_t qo = (size_t)(i0 + l15) * K_ + quad * 8;
    short8 qh0 = *(const short8*)(Qh + qo);
    short8 qh1 = *(const short8*)(Qh + qo + 32);
    short8 ql0 = *(const short8*)(Ql + qo);
    short8 ql1 = *(const short8*)(Ql + qo + 32);

    f32x4 s[16];
    #pragma unroll
    for (int t = 0; t < 16; ++t) {
        const int j0 = (w * 16 + t) * 16;
        const size_t ko = (size_t)(j0 + l15) * K_ + quad * 8;
        short8 kh0 = *(const short8*)(Kh + ko);
        short8 kh1 = *(const short8*)(Kh + ko + 32);
        f32x4 acc = {0.f, 0.f, 0.f, 0.f};
        acc = mfma16(qh0, kh0, acc);
        acc = mfma16(ql0, kh0, acc);
        acc = mfma16(qh1, kh1, acc);
        acc = mfma16(ql1, kh1, acc);
        s[t] = acc;
    }

    // ---- row max & min ----
    float mx[4], mn[4];
    #pragma unroll
    for (int r = 0; r < 4; ++r) { mx[r] = s[0][r]; mn[r] = s[0][r]; }
    #pragma unroll
    for (int t = 1; t < 16; ++t)
        #pragma unroll
        for (int r = 0; r < 4; ++r) {
            mx[r] = fmaxf(mx[r], s[t][r]);
            mn[r] = fminf(mn[r], s[t][r]);
        }
    #pragma unroll
    for (int r = 0; r < 4; ++r) {
        float a = mx[r], b = mn[r];
        a = fmaxf(a, __shfl_xor(a, 1));  b = fminf(b, __shfl_xor(b, 1));
        a = fmaxf(a, __shfl_xor(a, 2));  b = fminf(b, __shfl_xor(b, 2));
        a = fmaxf(a, __shfl_xor(a, 4));  b = fminf(b, __shfl_xor(b, 4));
        a = fmaxf(a, __shfl_xor(a, 8));  b = fminf(b, __shfl_xor(b, 8));
        mx[r] = a; mn[r] = b;
    }

    __shared__ float redmax[8][16], redmin[8][16], redsum[8][16];
    if (l15 == 0) {
        #pragma unroll
        for (int r = 0; r < 4; ++r) {
            redmax[w][quad * 4 + r] = mx[r];
            redmin[w][quad * 4 + r] = mn[r];
        }
    }
    __syncthreads();

    float invmax[4], nzmax[4];
    #pragma unroll
    for (int r = 0; r < 4; ++r) {
        float mm = redmax[0][quad * 4 + r], nn = redmin[0][quad * 4 + r];
        #pragma unroll
        for (int ww = 1; ww < 8; ++ww) {
            mm = fmaxf(mm, redmax[ww][quad * 4 + r]);
            nn = fminf(nn, redmin[ww][quad * 4 + r]);
        }
        invmax[r] = 1.0f / mm;
        // z = qkt/rmax; true max of z = max(1, rmin/rmax) (handles rmax<0)
        nzmax[r] = -fmaxf(1.0f, nn * invmax[r]);
    }

    // ---- exp(z - zmax) in place + row sum ----
    float lsum[4] = {0.f, 0.f, 0.f, 0.f};
    #pragma unroll
    for (int t = 0; t < 16; ++t)
        #pragma unroll
        for (int r = 0; r < 4; ++r) {
            float e = __expf(fmaf(s[t][r], invmax[r], nzmax[r]));
            s[t][r] = e;
            lsum[r] += e;
        }
    #pragma unroll
    for (int r = 0; r < 4; ++r) {
        float v = lsum[r];
        v += __shfl_xor(v, 1); v += __shfl_xor(v, 2);
        v += __shfl_xor(v, 4); v += __shfl_xor(v, 8);
        lsum[r] = v;
    }
    if (l15 == 0) {
        #pragma unroll
        for (int r = 0; r < 4; ++r) redsum[w][quad * 4 + r] = lsum[r];
    }
    __syncthreads();

    float invsum[4];
    #pragma unroll
    for (int r = 0; r < 4; ++r) {
        float ss = 0.f;
        #pragma unroll
        for (int ww = 0; ww < 8; ++ww) ss += redsum[ww][quad * 4 + r];
        invsum[r] = 1.0f / ss;
    }

    // ---- normalize + store fp32 ----
    float* ob = out + (size_t)bb * M_ * M_;
    #pragma unroll
    for (int t = 0; t < 16; ++t) {
        const int j0 = (w * 16 + t) * 16;
        #pragma unroll
        for (int r = 0; r < 4; ++r) {
            size_t idx = (size_t)(i0 + quad * 4 + r) * M_ + j0 + l15;
            ob[idx] = s[t][r] * invsum[r];
        }
    }
}

// ---------------------------------------------------------------------------
extern "C" void kernel_launch(void* const* d_in, const int* in_sizes, int n_in,
                              void* d_out, int out_size, void* d_ws, size_t ws_size,
                              hipStream_t stream)
{
    (void)in_sizes; (void)n_in; (void)out_size; (void)ws_size;
    const float* x   = (const float*)d_in[0];
    const float* qW1 = (const float*)d_in[1];
    const float* qb1 = (const float*)d_in[2];
    const float* qW2 = (const float*)d_in[3];
    const float* qb2 = (const float*)d_in[4];
    const float* kW1 = (const float*)d_in[5];
    const float* kb1 = (const float*)d_in[6];
    const float* kW2 = (const float*)d_in[7];
    const float* kb2 = (const float*)d_in[8];
    short* ws  = (short*)d_ws;
    float* out = (float*)d_out;

    prep_w<<<dim3(128, 4), 256, 0, stream>>>(qW1, kW1, qW2, kW2, ws);
    mlp_kernel<<<dim3(ROWS / 32, 2), 128, 0, stream>>>(x, ws, qb1, kb1, qb2, kb2);
    scores_kernel<<<dim3(M_ / 16, B_), 512, 0, stream>>>(ws, out);
}

// Round 4
// 460.112 us; speedup vs baseline: 1.0792x; 1.0315x over previous
//
#include <hip/hip_runtime.h>

// Problem dims
#define B_   16
#define M_   2048
#define D_   128
#define H_   256
#define K_   64
#define ROWS (B_ * M_)   // 32768

typedef short short8 __attribute__((ext_vector_type(8)));
typedef float f32x4  __attribute__((ext_vector_type(4)));

// ws layout (in short/bf16 elements)
// Q stored hi+lo (removes q-side rounding); K stored hi only (error budget:
// k-rounding alone -> absmax ~5e-3 vs 1.55e-2 threshold, measured r3).
static constexpr size_t OFF_QHI = 0;                           // [ROWS][64]
static constexpr size_t OFF_QLO = (size_t)ROWS * K_;
static constexpr size_t OFF_KHI = 2 * (size_t)ROWS * K_;
static constexpr size_t OFF_W1H = 3 * (size_t)ROWS * K_;       // [2][H_][D_]
static constexpr size_t OFF_W1L = OFF_W1H + 2 * (size_t)D_ * H_;
static constexpr size_t OFF_W2H = OFF_W1L + 2 * (size_t)D_ * H_;  // [2][K_][H_]
static constexpr size_t OFF_W2L = OFF_W2H + 2 * (size_t)H_ * K_;

static __device__ __forceinline__ float bf2f(short u) {
    union { unsigned int u; float f; } c;
    c.u = ((unsigned int)(unsigned short)u) << 16;
    return c.f;
}
static __device__ __forceinline__ short f2bf(float f) {
    union { float f; unsigned int u; } c; c.f = f;
    unsigned int u = c.u + 0x7fffu + ((c.u >> 16) & 1u);   // RNE
    return (short)(u >> 16);
}
static __device__ __forceinline__ void split2(float v, short& hi, short& lo) {
    hi = f2bf(v);
    lo = f2bf(v - bf2f(hi));
}
static __device__ __forceinline__ f32x4 mfma16(short8 a, short8 b, f32x4 c) {
    return __builtin_amdgcn_mfma_f32_16x16x32_bf16(a, b, c, 0, 0, 0);
}

// ---------------------------------------------------------------------------
// k0: transpose + hi/lo split weights (fp32 -> bf16 planes)
// ---------------------------------------------------------------------------
__global__ __launch_bounds__(256) void prep_w(
    const float* __restrict__ qW1, const float* __restrict__ kW1,
    const float* __restrict__ qW2, const float* __restrict__ kW2,
    short* __restrict__ ws)
{
    const int which = blockIdx.y;
    const float* src; short* dhi; short* dlo; int N, Kd;
    if (which == 0)      { src = qW1; dhi = ws + OFF_W1H;            dlo = ws + OFF_W1L;            N = H_; Kd = D_; }
    else if (which == 1) { src = kW1; dhi = ws + OFF_W1H + D_ * H_;  dlo = ws + OFF_W1L + D_ * H_;  N = H_; Kd = D_; }
    else if (which == 2) { src = qW2; dhi = ws + OFF_W2H;            dlo = ws + OFF_W2L;            N = K_; Kd = H_; }
    else                 { src = kW2; dhi = ws + OFF_W2H + H_ * K_;  dlo = ws + OFF_W2L + H_ * K_;  N = K_; Kd = H_; }
    int idx = blockIdx.x * 256 + threadIdx.x;
    if (idx < N * Kd) {
        int n = idx / Kd, k = idx % Kd;
        float v = src[(size_t)k * N + n];   // dst[n][k] = src[k][n]
        short hi, lo; split2(v, hi, lo);
        dhi[idx] = hi; dlo[idx] = lo;
    }
}

// ---------------------------------------------------------------------------
// k1: fused MLP per wave (16 rows), fp32 in, split-bf16 MFMA arithmetic.
//   head 0 -> Q hi+lo planes; head 1 -> K hi plane only.
// Block = 128 thr (2 waves). grid = (ROWS/32, 2 heads).
// ---------------------------------------------------------------------------
__global__ __launch_bounds__(128) void mlp_kernel(
    const float* __restrict__ x,     // [ROWS][128] fp32
    short* __restrict__ ws,
    const float* __restrict__ qb1, const float* __restrict__ kb1,
    const float* __restrict__ qb2, const float* __restrict__ kb2)
{
    const int head = blockIdx.y;
    const short* W1H = ws + OFF_W1H + (size_t)head * (D_ * H_);  // [256][128]
    const short* W1L = ws + OFF_W1L + (size_t)head * (D_ * H_);
    const short* W2H = ws + OFF_W2H + (size_t)head * (H_ * K_);  // [64][256]
    const short* W2L = ws + OFF_W2L + (size_t)head * (H_ * K_);
    const float* b1  = head ? kb1 : qb1;
    const float* b2  = head ? kb2 : qb2;
    short* ohi       = ws + (head ? OFF_KHI : OFF_QHI);          // [ROWS][64]
    short* olo       = ws + OFF_QLO;                             // head 0 only

    const int tid  = threadIdx.x;
    const int w    = tid >> 6;        // wave 0..1
    const int lane = tid & 63;
    const int l15  = lane & 15;
    const int quad = lane >> 4;
    const int r0   = (blockIdx.x * 2 + w) * 16;   // this wave's 16 rows

    // per-wave h tile, split hi/lo; row stride 264 shorts (16B-aligned)
    __shared__ __align__(16) short hs[2][2][16][264];

    // ---- A-frags from x: A[m=l15][k=quad*8+j], split hi/lo; float4 loads ----
    short8 ah[4], al[4];
    const float* xrow = x + (size_t)(r0 + l15) * D_ + quad * 8;
    #pragma unroll
    for (int ks = 0; ks < 4; ++ks) {
        float4 v0 = *(const float4*)(xrow + ks * 32);
        float4 v1 = *(const float4*)(xrow + ks * 32 + 4);
        float vv[8] = {v0.x, v0.y, v0.z, v0.w, v1.x, v1.y, v1.z, v1.w};
        #pragma unroll
        for (int j = 0; j < 8; ++j) {
            short hi, lo; split2(vv[j], hi, lo);
            ah[ks][j] = hi; al[ks][j] = lo;
        }
    }

    // ---- GEMM1 ----
    #pragma unroll
    for (int jt = 0; jt < 16; ++jt) {             // 16 col-tiles of H=256
        f32x4 acc = {0.f, 0.f, 0.f, 0.f};
        const size_t wro = (size_t)(jt * 16 + l15) * D_ + quad * 8;
        #pragma unroll
        for (int ks = 0; ks < 4; ++ks) {
            short8 bh = *(const short8*)(W1H + wro + ks * 32);
            short8 bl = *(const short8*)(W1L + wro + ks * 32);
            acc = mfma16(ah[ks], bh, acc);
            acc = mfma16(al[ks], bh, acc);
            acc = mfma16(ah[ks], bl, acc);
        }
        float bias = b1[jt * 16 + l15];           // C col = l15
        #pragma unroll
        for (int r = 0; r < 4; ++r) {             // C row = quad*4+r
            float v = acc[r] + bias;
            v = v > 0.f ? v : 0.f;
            short hi, lo; split2(v, hi, lo);
            hs[w][0][quad * 4 + r][jt * 16 + l15] = hi;
            hs[w][1][quad * 4 + r][jt * 16 + l15] = lo;
        }
    }
    // no barrier: each wave reads only its own LDS region

    // ---- GEMM2: A-frags from hs ----
    short8 gh[8], gl[8];
    #pragma unroll
    for (int ks = 0; ks < 8; ++ks) {
        gh[ks] = *(const short8*)&hs[w][0][l15][ks * 32 + quad * 8];
        gl[ks] = *(const short8*)&hs[w][1][l15][ks * 32 + quad * 8];
    }
    #pragma unroll
    for (int jt = 0; jt < 4; ++jt) {              // 4 col-tiles of K=64
        f32x4 acc = {0.f, 0.f, 0.f, 0.f};
        const size_t wro = (size_t)(jt * 16 + l15) * H_ + quad * 8;
        #pragma unroll
        for (int ks = 0; ks < 8; ++ks) {
            short8 bh = *(const short8*)(W2H + wro + ks * 32);
            short8 bl = *(const short8*)(W2L + wro + ks * 32);
            acc = mfma16(gh[ks], bh, acc);
            acc = mfma16(gl[ks], bh, acc);
            acc = mfma16(gh[ks], bl, acc);
        }
        float bias = b2[jt * 16 + l15];
        #pragma unroll
        for (int r = 0; r < 4; ++r) {
            float v = acc[r] + bias;
            size_t oi = (size_t)(r0 + quad * 4 + r) * K_ + jt * 16 + l15;
            if (head == 0) {
                short hi, lo; split2(v, hi, lo);
                ohi[oi] = hi; olo[oi] = lo;
            } else {
                ohi[oi] = f2bf(v);
            }
        }
    }
}

// ---------------------------------------------------------------------------
// k2: scores + max-division softmax. Block = 512 thr (8 waves), 16 Q-rows.
// 1D grid 2048, XCD-swizzled: xcd = flat&7 serves batches {xcd, xcd+8} only
// -> per-XCD L2 working set ~2 MB (K+Q of 2 batches), L2-resident re-reads.
// __launch_bounds__(512,4): VGPR cap 128 -> 2 blocks/CU so one block's
// store phase overlaps the next block's load/MFMA phase.
// Output stores are nontemporal: 268 MB stream must not evict K/Q from L2.
// ---------------------------------------------------------------------------
__global__ __launch_bounds__(512, 4) void scores_kernel(
    const short* __restrict__ ws,
    float* __restrict__ out)          // [B][M][M] fp32
{
    const int flat = blockIdx.x;
    const int xcd  = flat & 7;
    const int slot = flat >> 3;
    const int bb   = (slot & 1) * 8 + xcd;   // batch
    const int i0   = (slot >> 1) * 16;       // Q-row tile
    const int tid  = threadIdx.x;
    const int w    = tid >> 6;        // wave 0..7
    const int lane = tid & 63;
    const int l15  = lane & 15;
    const int quad = lane >> 4;

    const short* Qh = ws + OFF_QHI + (size_t)bb * M_ * K_;
    const short* Ql = ws + OFF_QLO + (size_t)bb * M_ * K_;
    const short* Kh = ws + OFF_KHI + (size_t)bb * M_ * K_;

    // Q A-frags for rows i0..i0+15
    const size_t qo = (size_t)(i0 + l15) * K_ + quad * 8;
    short8 qh0 = *(const short8*)(Qh + qo);
    short8 qh1 = *(const short8*)(Qh + qo + 32);
    short8 ql0 = *(const short8*)(Ql + qo);
    short8 ql1 = *(const short8*)(Ql + qo + 32);

    f32x4 s[16];
    #pragma unroll
    for (int t = 0; t < 16; ++t) {
        const int j0 = (w * 16 + t) * 16;
        const size_t ko = (size_t)(j0 + l15) * K_ + quad * 8;
        short8 kh0 = *(const short8*)(Kh + ko);
        short8 kh1 = *(const short8*)(Kh + ko + 32);
        f32x4 acc = {0.f, 0.f, 0.f, 0.f};
        acc = mfma16(qh0, kh0, acc);
        acc = mfma16(ql0, kh0, acc);
        acc = mfma16(qh1, kh1, acc);
        acc = mfma16(ql1, kh1, acc);
        s[t] = acc;
    }

    // ---- row max & min ----
    float mx[4], mn[4];
    #pragma unroll
    for (int r = 0; r < 4; ++r) { mx[r] = s[0][r]; mn[r] = s[0][r]; }
    #pragma unroll
    for (int t = 1; t < 16; ++t)
        #pragma unroll
        for (int r = 0; r < 4; ++r) {
            mx[r] = fmaxf(mx[r], s[t][r]);
            mn[r] = fminf(mn[r], s[t][r]);
        }
    #pragma unroll
    for (int r = 0; r < 4; ++r) {
        float a = mx[r], b = mn[r];
        a = fmaxf(a, __shfl_xor(a, 1));  b = fminf(b, __shfl_xor(b, 1));
        a = fmaxf(a, __shfl_xor(a, 2));  b = fminf(b, __shfl_xor(b, 2));
        a = fmaxf(a, __shfl_xor(a, 4));  b = fminf(b, __shfl_xor(b, 4));
        a = fmaxf(a, __shfl_xor(a, 8));  b = fminf(b, __shfl_xor(b, 8));
        mx[r] = a; mn[r] = b;
    }

    __shared__ float redmax[8][16], redmin[8][16], redsum[8][16];
    if (l15 == 0) {
        #pragma unroll
        for (int r = 0; r < 4; ++r) {
            redmax[w][quad * 4 + r] = mx[r];
            redmin[w][quad * 4 + r] = mn[r];
        }
    }
    __syncthreads();

    float invmax[4], nzmax[4];
    #pragma unroll
    for (int r = 0; r < 4; ++r) {
        float mm = redmax[0][quad * 4 + r], nn = redmin[0][quad * 4 + r];
        #pragma unroll
        for (int ww = 1; ww < 8; ++ww) {
            mm = fmaxf(mm, redmax[ww][quad * 4 + r]);
            nn = fminf(nn, redmin[ww][quad * 4 + r]);
        }
        invmax[r] = 1.0f / mm;
        // z = qkt/rmax; true max of z = max(1, rmin/rmax) (handles rmax<0)
        nzmax[r] = -fmaxf(1.0f, nn * invmax[r]);
    }

    // ---- exp(z - zmax) in place + row sum ----
    float lsum[4] = {0.f, 0.f, 0.f, 0.f};
    #pragma unroll
    for (int t = 0; t < 16; ++t)
        #pragma unroll
        for (int r = 0; r < 4; ++r) {
            float e = __expf(fmaf(s[t][r], invmax[r], nzmax[r]));
            s[t][r] = e;
            lsum[r] += e;
        }
    #pragma unroll
    for (int r = 0; r < 4; ++r) {
        float v = lsum[r];
        v += __shfl_xor(v, 1); v += __shfl_xor(v, 2);
        v += __shfl_xor(v, 4); v += __shfl_xor(v, 8);
        lsum[r] = v;
    }
    if (l15 == 0) {
        #pragma unroll
        for (int r = 0; r < 4; ++r) redsum[w][quad * 4 + r] = lsum[r];
    }
    __syncthreads();

    float invsum[4];
    #pragma unroll
    for (int r = 0; r < 4; ++r) {
        float ss = 0.f;
        #pragma unroll
        for (int ww = 0; ww < 8; ++ww) ss += redsum[ww][quad * 4 + r];
        invsum[r] = 1.0f / ss;
    }

    // ---- normalize + nontemporal store fp32 ----
    float* ob = out + (size_t)bb * M_ * M_;
    #pragma unroll
    for (int t = 0; t < 16; ++t) {
        const int j0 = (w * 16 + t) * 16;
        #pragma unroll
        for (int r = 0; r < 4; ++r) {
            size_t idx = (size_t)(i0 + quad * 4 + r) * M_ + j0 + l15;
            __builtin_nontemporal_store(s[t][r] * invsum[r], &ob[idx]);
        }
    }
}

// ---------------------------------------------------------------------------
extern "C" void kernel_launch(void* const* d_in, const int* in_sizes, int n_in,
                              void* d_out, int out_size, void* d_ws, size_t ws_size,
                              hipStream_t stream)
{
    (void)in_sizes; (void)n_in; (void)out_size; (void)ws_size;
    const float* x   = (const float*)d_in[0];
    const float* qW1 = (const float*)d_in[1];
    const float* qb1 = (const float*)d_in[2];
    const float* qW2 = (const float*)d_in[3];
    const float* qb2 = (const float*)d_in[4];
    const float* kW1 = (const float*)d_in[5];
    const float* kb1 = (const float*)d_in[6];
    const float* kW2 = (const float*)d_in[7];
    const float* kb2 = (const float*)d_in[8];
    short* ws  = (short*)d_ws;
    float* out = (float*)d_out;

    prep_w<<<dim3(128, 4), 256, 0, stream>>>(qW1, kW1, qW2, kW2, ws);
    mlp_kernel<<<dim3(ROWS / 32, 2), 128, 0, stream>>>(x, ws, qb1, kb1, qb2, kb2);
    scores_kernel<<<dim3(2048), 512, 0, stream>>>(ws, out);
}